// Round 17
// baseline (233.633 us; speedup 1.0000x reference)
//
#include <hip/hip_runtime.h>
#include <hip/hip_bf16.h>

#define D 128
#define K1 384
#define H 256
#define O 128
#define BE 64
#define GRIDP 256
#define LDF (K1 + 8)   // fallback path feat leading dim
#define LDHF (H + 8)

typedef __attribute__((ext_vector_type(8))) short bf16x8;
typedef __attribute__((ext_vector_type(4))) float f32x4;

// XOR-swizzle (bits 3-5 of ushort col index; aligned 4/8-elem groups stay contiguous)
#define SSW(row, col) ((row) * 128 + ((col) ^ (((row) & 7) << 3)))   // staging tiles, col<128
#define HSW(row, col) ((row) * 256 + ((col) ^ (((row) & 7) << 3)))   // h tile, col<256

// lgkm-only barrier: orders LDS, does NOT drain vmcnt (prefetch stays in flight).
#define LGKM_BARRIER()                                                 \
    do {                                                               \
        asm volatile("s_waitcnt lgkmcnt(0)\n\ts_barrier" ::: "memory");\
        __builtin_amdgcn_sched_barrier(0);                             \
    } while (0)

__device__ inline ushort f2b(float f) {
    union { float f; unsigned u; } v; v.f = f;
    unsigned u = v.u;
    unsigned r = (u + 0x7fffu + ((u >> 16) & 1u)) >> 16;   // RNE
    return (ushort)r;
}
__device__ inline ushort4 cvt4(float4 v) {
    ushort4 u; u.x = f2b(v.x); u.y = f2b(v.y); u.z = f2b(v.z); u.w = f2b(v.w); return u;
}
__device__ inline bf16x8 cvt8(f32x4 a, f32x4 b) {
    union { bf16x8 v; ushort u[8]; } w;
    w.u[0] = f2b(a[0]); w.u[1] = f2b(a[1]); w.u[2] = f2b(a[2]); w.u[3] = f2b(a[3]);
    w.u[4] = f2b(b[0]); w.u[5] = f2b(b[1]); w.u[6] = f2b(b[2]); w.u[7] = f2b(b[3]);
    return w.v;
}

// W1t[n][k] = bf16(W1[k][n]) (n<256,k<384) ; W2t[o][k] = bf16(W2[k][o]) (o<128,k<256)
__global__ void prep_weights(const float* __restrict__ W1, const float* __restrict__ W2,
                             ushort* __restrict__ W1t, ushort* __restrict__ W2t) {
    int tid = blockIdx.x * blockDim.x + threadIdx.x;
    if (tid < 256 * 384) {
        int n = tid / 384, k = tid % 384;
        W1t[tid] = f2b(W1[k * 256 + n]);
    } else {
        int t2 = tid - 256 * 384;
        if (t2 < 128 * 256) {
            int o = t2 / 256, k = t2 % 256;
            W2t[t2] = f2b(W2[k * 128 + o]);
        }
    }
}

// Xb[n][d] = bf16(x[n][d]) — 12.8 MB gather table
__global__ __launch_bounds__(256)
void prep_x(const float* __restrict__ x, ushort* __restrict__ Xb, long total8) {
    long t = (long)blockIdx.x * blockDim.x + threadIdx.x;
    if (t < total8) {
        const float* src = x + t * 8;
        float4 v0 = ((const float4*)src)[0], v1 = ((const float4*)src)[1];
        union { bf16x8 v; ushort4 u[2]; } w;
        w.u[0] = cvt4(v0); w.u[1] = cvt4(v1);
        *(bf16x8*)(Xb + t * 8) = w.v;
    }
}

// R17: 2-tile software pipeline. Epoch = {barrier A -> phase2(t-1) || phase1(t) ||
// loads(t+1) || staging(t+1) || out-store(t-1) -> barrier B -> sHwrite(t)}.
// sA double-buffered (2x48KB), sH single (32KB) => 128KB LDS, 2 barriers/tile.
// Phase-1 uses R16's swapped MFMA (D[h-col][edge], vectorized sH write).
__global__ __launch_bounds__(512, 2)
void edge_mlp14(const float* __restrict__ ea, const int* __restrict__ eidx,
                const ushort* __restrict__ Xb,
                const ushort* __restrict__ W1t, const ushort* __restrict__ W2t,
                const float* __restrict__ b1, const float* __restrict__ b2,
                float* __restrict__ out, int E, int ntiles) {
    __shared__ __align__(16) ushort sBuf[65536];   // 128 KB: sA0 | sA1 | sH
    ushort* sH = sBuf + 49152;

    const int tid = threadIdx.x;
    const int wave = tid >> 6, lane = tid & 63;
    const int row16 = lane & 15, kgrp = lane >> 4;
    const int srow = tid >> 3, oct = tid & 7;     // staging: 8 threads per edge-row

    // ---- persistent per-wave weight fragments ----
    bf16x8 w1f[12][2];      // phase1 (swapped): h-cols [wave*32,+32), ks spans K=384
    #pragma unroll
    for (int ks = 0; ks < 12; ++ks)
        #pragma unroll
        for (int fc = 0; fc < 2; ++fc)
            w1f[ks][fc] = *(const bf16x8*)(W1t + (wave * 32 + fc * 16 + row16) * K1 + ks * 32 + kgrp * 8);
    bf16x8 w2f[8];          // phase2: out cols [wave*16, +16)
    #pragma unroll
    for (int ks = 0; ks < 8; ++ks)
        w2f[ks] = *(const bf16x8*)(W2t + (wave * 16 + row16) * H + ks * 32 + kgrp * 8);
    float4 b1q[2];
    #pragma unroll
    for (int fc = 0; fc < 2; ++fc)
        b1q[fc] = *(const float4*)(b1 + wave * 32 + fc * 16 + kgrp * 4);
    const float b2v = b2[wave * 16 + row16];

    int t = blockIdx.x;
    if (t >= ntiles) return;

    bf16x8 pxs[2], pxr[2];
    f32x4  pea[4];

    // ---- prologue: stage tile t into sA[0] ----
    {
        long se = (long)t * BE + srow; if (se >= E) se = E - 1;
        int2 ei = *(const int2*)(eidx + 2 * se);
        const ushort* ps = Xb + (long)ei.x * D + oct * 16;
        const ushort* pr = Xb + (long)ei.y * D + oct * 16;
        const float*  pe = ea + se * D + oct * 16;
        #pragma unroll
        for (int j = 0; j < 2; ++j) pxs[j] = *(const bf16x8*)(ps + j * 8);
        #pragma unroll
        for (int j = 0; j < 2; ++j) pxr[j] = *(const bf16x8*)(pr + j * 8);
        #pragma unroll
        for (int j = 0; j < 4; ++j) pea[j] = ((const f32x4*)pe)[j];

        #pragma unroll
        for (int j = 0; j < 2; ++j) *(bf16x8*)(sBuf + SSW(srow, oct * 16 + j * 8)) = pxs[j];
        #pragma unroll
        for (int j = 0; j < 2; ++j) *(bf16x8*)(sBuf + 8192 + SSW(srow, oct * 16 + j * 8)) = pxr[j];
        *(bf16x8*)(sBuf + 16384 + SSW(srow, oct * 16 + 0)) = cvt8(pea[0], pea[1]);
        *(bf16x8*)(sBuf + 16384 + SSW(srow, oct * 16 + 8)) = cvt8(pea[2], pea[3]);
    }

    int p = 0;
    int tprev = -1;
    int tn = t + GRIDP;
    int2 ei2;
    {
        int tc = (tn < ntiles) ? tn : (ntiles - 1);
        long se = (long)tc * BE + srow; if (se >= E) se = E - 1;
        ei2 = *(const int2*)(eidx + 2 * se);
    }

    for (;;) {
        LGKM_BARRIER();                 // A: sA[p] (staged) + sH(tprev) visible
        const bool hasNext = (tn < ntiles);
        if (hasNext) {
            long sen = (long)tn * BE + srow; if (sen >= E) sen = E - 1;
            const ushort* ps = Xb + (long)ei2.x * D + oct * 16;
            const ushort* pr = Xb + (long)ei2.y * D + oct * 16;
            const float*  pe = ea + sen * D + oct * 16;
            #pragma unroll
            for (int j = 0; j < 2; ++j) pxs[j] = *(const bf16x8*)(ps + j * 8);
            #pragma unroll
            for (int j = 0; j < 2; ++j) pxr[j] = *(const bf16x8*)(pr + j * 8);
            #pragma unroll
            for (int j = 0; j < 4; ++j) pea[j] = ((const f32x4*)pe)[j];
            int tnn = tn + GRIDP;
            int tc = (tnn < ntiles) ? tnn : (ntiles - 1);
            long se2 = (long)tc * BE + srow; if (se2 >= E) se2 = E - 1;
            ei2 = *(const int2*)(eidx + 2 * se2);
        }

        // ---- phase 2 of PREVIOUS tile (reads sH; independent of phase 1 below) ----
        f32x4 acc2[4];
        if (tprev >= 0) {
            #pragma unroll
            for (int fr = 0; fr < 4; ++fr) acc2[fr] = (f32x4){0,0,0,0};
            #pragma unroll
            for (int ks = 0; ks < 8; ++ks) {
                bf16x8 a[4];
                #pragma unroll
                for (int fr = 0; fr < 4; ++fr)
                    a[fr] = *(const bf16x8*)(sH + HSW(fr * 16 + row16, ks * 32 + kgrp * 8));
                #pragma unroll
                for (int fr = 0; fr < 4; ++fr)
                    acc2[fr] = __builtin_amdgcn_mfma_f32_16x16x32_bf16(a[fr], w2f[ks], acc2[fr], 0, 0, 0);
            }
        }

        // ---- phase 1 of CURRENT tile (swapped): acc[fe][fc] -> D[h-col][edge] ----
        const ushort* sA = sBuf + (p ? 24576 : 0);
        f32x4 acc[4][2];
        #pragma unroll
        for (int fe = 0; fe < 4; ++fe) { acc[fe][0] = (f32x4){0,0,0,0}; acc[fe][1] = (f32x4){0,0,0,0}; }
        #pragma unroll
        for (int ks = 0; ks < 12; ++ks) {
            const ushort* sP = sA + ((ks < 4) ? 0 : ((ks < 8) ? 8192 : 16384));
            const int kl = (ks & 3) * 32 + kgrp * 8;
            bf16x8 a[4];
            #pragma unroll
            for (int fe = 0; fe < 4; ++fe)
                a[fe] = *(const bf16x8*)(sP + SSW(fe * 16 + row16, kl));
            #pragma unroll
            for (int fe = 0; fe < 4; ++fe) {
                acc[fe][0] = __builtin_amdgcn_mfma_f32_16x16x32_bf16(w1f[ks][0], a[fe], acc[fe][0], 0, 0, 0);
                acc[fe][1] = __builtin_amdgcn_mfma_f32_16x16x32_bf16(w1f[ks][1], a[fe], acc[fe][1], 0, 0, 0);
            }
        }

        // ---- out-store(tprev) ----
        if (tprev >= 0) {
            const long e0p = (long)tprev * BE;
            #pragma unroll
            for (int fr = 0; fr < 4; ++fr)
                #pragma unroll
                for (int r = 0; r < 4; ++r) {
                    long erow = e0p + fr * 16 + kgrp * 4 + r;
                    if (erow < E) out[erow * O + wave * 16 + row16] = acc2[fr][r] + b2v;
                }
        }

        // ---- staging write(t+1) -> sA[p^1] (last read one epoch ago) ----
        if (hasNext) {
            ushort* sB = sBuf + (p ? 0 : 24576);
            #pragma unroll
            for (int j = 0; j < 2; ++j) *(bf16x8*)(sB + SSW(srow, oct * 16 + j * 8)) = pxs[j];
            #pragma unroll
            for (int j = 0; j < 2; ++j) *(bf16x8*)(sB + 8192 + SSW(srow, oct * 16 + j * 8)) = pxr[j];
            *(bf16x8*)(sB + 16384 + SSW(srow, oct * 16 + 0)) = cvt8(pea[0], pea[1]);
            *(bf16x8*)(sB + 16384 + SSW(srow, oct * 16 + 8)) = cvt8(pea[2], pea[3]);
        }

        LGKM_BARRIER();                 // B: all phase-2 reads of sH done

        // ---- sH write(t): relu(acc) -> sH (visible at next barrier A) ----
        #pragma unroll
        for (int fe = 0; fe < 4; ++fe) {
            int erow = fe * 16 + row16;
            int base = erow * 256;
            int swz = (erow & 7) << 3;
            #pragma unroll
            for (int fc = 0; fc < 2; ++fc) {
                int colb = wave * 32 + fc * 16 + kgrp * 4;
                ushort4 u;
                u.x = f2b(fmaxf(acc[fe][fc][0] + b1q[fc].x, 0.f));
                u.y = f2b(fmaxf(acc[fe][fc][1] + b1q[fc].y, 0.f));
                u.z = f2b(fmaxf(acc[fe][fc][2] + b1q[fc].z, 0.f));
                u.w = f2b(fmaxf(acc[fe][fc][3] + b1q[fc].w, 0.f));
                *(ushort4*)(sH + base + (colb ^ swz)) = u;
            }
        }

        tprev = t; t = tn; tn += GRIDP;
        if (t >= ntiles) break;
        p ^= 1;
    }

    // ---- epilogue: phase2 + store of the last tile ----
    LGKM_BARRIER();
    {
        f32x4 acc2[4];
        #pragma unroll
        for (int fr = 0; fr < 4; ++fr) acc2[fr] = (f32x4){0,0,0,0};
        #pragma unroll
        for (int ks = 0; ks < 8; ++ks) {
            bf16x8 a[4];
            #pragma unroll
            for (int fr = 0; fr < 4; ++fr)
                a[fr] = *(const bf16x8*)(sH + HSW(fr * 16 + row16, ks * 32 + kgrp * 8));
            #pragma unroll
            for (int fr = 0; fr < 4; ++fr)
                acc2[fr] = __builtin_amdgcn_mfma_f32_16x16x32_bf16(a[fr], w2f[ks], acc2[fr], 0, 0, 0);
        }
        const long e0p = (long)tprev * BE;
        #pragma unroll
        for (int fr = 0; fr < 4; ++fr)
            #pragma unroll
            for (int r = 0; r < 4; ++r) {
                long erow = e0p + fr * 16 + kgrp * 4 + r;
                if (erow < E) out[erow * O + wave * 16 + row16] = acc2[fr][r] + b2v;
            }
    }
}

// ---------------- fallback kernel: used only if ws too small ----------------
__global__ __launch_bounds__(256, 2)
void edge_mlp(const float* __restrict__ x, const float* __restrict__ ea,
              const int* __restrict__ eidx,
              const float* __restrict__ b1, const float* __restrict__ b2,
              const ushort* __restrict__ W1t, const ushort* __restrict__ W2t,
              float* __restrict__ out, int E) {
    __shared__ ushort sF[64 * LDF];
    ushort* sH = sF;
    const int tid = threadIdx.x, wave = tid >> 6, lane = tid & 63;
    const int row16 = lane & 15, kgrp = lane >> 4;
    const long e0 = (long)blockIdx.x * 64;
    {
        int i = tid >> 2, p = tid & 3;
        long e = e0 + i; if (e >= E) e = E - 1;
        int s = eidx[2 * e], r = eidx[2 * e + 1];
        const float* src0 = x + (long)s * D + p * 32;
        const float* src1 = x + (long)r * D + p * 32;
        const float* src2 = ea + e * D + p * 32;
        ushort* dst = sF + i * LDF + p * 32;
        #pragma unroll
        for (int j = 0; j < 8; ++j) *(ushort4*)(dst + 0 * D + j * 4) = cvt4(((const float4*)src0)[j]);
        #pragma unroll
        for (int j = 0; j < 8; ++j) *(ushort4*)(dst + 1 * D + j * 4) = cvt4(((const float4*)src1)[j]);
        #pragma unroll
        for (int j = 0; j < 8; ++j) *(ushort4*)(dst + 2 * D + j * 4) = cvt4(((const float4*)src2)[j]);
    }
    __syncthreads();
    f32x4 acc[4][4];
    #pragma unroll
    for (int a = 0; a < 4; ++a)
        #pragma unroll
        for (int b = 0; b < 4; ++b) acc[a][b] = (f32x4){0,0,0,0};
    const int wcol = wave * 64;
    for (int k0 = 0; k0 < K1; k0 += 32) {
        bf16x8 a[4], b[4];
        #pragma unroll
        for (int fr = 0; fr < 4; ++fr)
            a[fr] = *(const bf16x8*)(sF + (fr * 16 + row16) * LDF + k0 + kgrp * 8);
        #pragma unroll
        for (int fc = 0; fc < 4; ++fc)
            b[fc] = *(const bf16x8*)(W1t + (wcol + fc * 16 + row16) * K1 + k0 + kgrp * 8);
        #pragma unroll
        for (int fr = 0; fr < 4; ++fr)
            #pragma unroll
            for (int fc = 0; fc < 4; ++fc)
                acc[fr][fc] = __builtin_amdgcn_mfma_f32_16x16x32_bf16(a[fr], b[fc], acc[fr][fc], 0, 0, 0);
    }
    __syncthreads();
    #pragma unroll
    for (int fc = 0; fc < 4; ++fc) {
        int col = wcol + fc * 16 + row16;
        float bv = b1[col];
        #pragma unroll
        for (int fr = 0; fr < 4; ++fr)
            #pragma unroll
            for (int r = 0; r < 4; ++r) {
                int row = fr * 16 + kgrp * 4 + r;
                sH[row * LDHF + col] = f2b(fmaxf(acc[fr][fc][r] + bv, 0.f));
            }
    }
    __syncthreads();
    f32x4 acc2[4][2];
    #pragma unroll
    for (int a = 0; a < 4; ++a)
        #pragma unroll
        for (int b = 0; b < 2; ++b) acc2[a][b] = (f32x4){0,0,0,0};
    const int wo = wave * 32;
    for (int k0 = 0; k0 < H; k0 += 32) {
        bf16x8 a[4], b[2];
        #pragma unroll
        for (int fr = 0; fr < 4; ++fr)
            a[fr] = *(const bf16x8*)(sH + (fr * 16 + row16) * LDHF + k0 + kgrp * 8);
        #pragma unroll
        for (int fc = 0; fc < 2; ++fc)
            b[fc] = *(const bf16x8*)(W2t + (wo + fc * 16 + row16) * H + k0 + kgrp * 8);
        #pragma unroll
        for (int fr = 0; fr < 4; ++fr)
            #pragma unroll
            for (int fc = 0; fc < 2; ++fc)
                acc2[fr][fc] = __builtin_amdgcn_mfma_f32_16x16x32_bf16(a[fr], b[fc], acc2[fr][fc], 0, 0, 0);
    }
    #pragma unroll
    for (int fc = 0; fc < 2; ++fc) {
        int col = wo + fc * 16 + row16;
        float bv = b2[col];
        #pragma unroll
        for (int fr = 0; fr < 4; ++fr)
            #pragma unroll
            for (int r = 0; r < 4; ++r) {
                long row = e0 + fr * 16 + kgrp * 4 + r;
                if (row < E) out[row * O + col] = acc2[fr][fc][r] + bv;
            }
    }
}

extern "C" void kernel_launch(void* const* d_in, const int* in_sizes, int n_in,
                              void* d_out, int out_size, void* d_ws, size_t ws_size,
                              hipStream_t stream) {
    const float* x  = (const float*)d_in[0];
    const float* ea = (const float*)d_in[1];
    const float* W1 = (const float*)d_in[2];
    const float* b1 = (const float*)d_in[3];
    const float* W2 = (const float*)d_in[4];
    const float* b2 = (const float*)d_in[5];
    const int* eidx = (const int*)d_in[6];
    float* out = (float*)d_out;

    const int E = in_sizes[1] / D;          // 500000
    const int N = in_sizes[0] / D;          // 50000

    ushort* W1t = (ushort*)d_ws;                    // 256*384
    ushort* W2t = W1t + 256 * 384;                  // 128*256
    ushort* Xb  = W2t + 128 * 256;                  // N*128 (12.8 MB)
    size_t need = ((size_t)(256 * 384 + 128 * 256) + (size_t)N * 128) * 2;

    prep_weights<<<512, 256, 0, stream>>>(W1, W2, W1t, W2t);

    if (ws_size >= need) {
        long total8 = (long)N * D / 8;
        int nbx = (int)((total8 + 255) / 256);
        prep_x<<<nbx, 256, 0, stream>>>(x, Xb, total8);
        int ntiles = (E + BE - 1) / BE;
        int grid = (ntiles < GRIDP) ? ntiles : GRIDP;
        edge_mlp14<<<grid, 512, 0, stream>>>(ea, eidx, Xb, W1t, W2t, b1, b2, out, E, ntiles);
    } else {
        int nb = (E + 63) / 64;
        edge_mlp<<<nb, 256, 0, stream>>>(x, ea, eidx, b1, b2, W1t, W2t, out, E);
    }
}

// Round 18
// 204.056 us; speedup vs baseline: 1.1449x; 1.1449x over previous
//
#include <hip/hip_runtime.h>
#include <hip/hip_bf16.h>

#define D 128
#define K1 384
#define H 256
#define O 128
#define BE 64
#define GRIDP 256
#define LDF (K1 + 8)   // fallback path feat leading dim
#define LDHF (H + 8)

typedef __attribute__((ext_vector_type(8))) short bf16x8;
typedef __attribute__((ext_vector_type(4))) float f32x4;

// XOR-swizzle (bits 3-5 of ushort col index; aligned 4/8-elem groups stay contiguous)
#define SSW(row, col) ((row) * 128 + ((col) ^ (((row) & 7) << 3)))   // staging tiles, col<128
#define HSW(row, col) ((row) * 256 + ((col) ^ (((row) & 7) << 3)))   // h tile, col<256

// lgkm-only barrier: orders LDS, does NOT drain vmcnt (prefetch stays in flight).
#define LGKM_BARRIER()                                                 \
    do {                                                               \
        asm volatile("s_waitcnt lgkmcnt(0)\n\ts_barrier" ::: "memory");\
        __builtin_amdgcn_sched_barrier(0);                             \
    } while (0)

__device__ inline ushort f2b(float f) {
    union { float f; unsigned u; } v; v.f = f;
    unsigned u = v.u;
    unsigned r = (u + 0x7fffu + ((u >> 16) & 1u)) >> 16;   // RNE
    return (ushort)r;
}
__device__ inline ushort4 cvt4(float4 v) {
    ushort4 u; u.x = f2b(v.x); u.y = f2b(v.y); u.z = f2b(v.z); u.w = f2b(v.w); return u;
}
__device__ inline bf16x8 cvt8(f32x4 a, f32x4 b) {
    union { bf16x8 v; ushort u[8]; } w;
    w.u[0] = f2b(a[0]); w.u[1] = f2b(a[1]); w.u[2] = f2b(a[2]); w.u[3] = f2b(a[3]);
    w.u[4] = f2b(b[0]); w.u[5] = f2b(b[1]); w.u[6] = f2b(b[2]); w.u[7] = f2b(b[3]);
    return w.v;
}

// W1t[n][k] = bf16(W1[k][n]) (n<256,k<384) ; W2t[o][k] = bf16(W2[k][o]) (o<128,k<256)
__global__ void prep_weights(const float* __restrict__ W1, const float* __restrict__ W2,
                             ushort* __restrict__ W1t, ushort* __restrict__ W2t) {
    int tid = blockIdx.x * blockDim.x + threadIdx.x;
    if (tid < 256 * 384) {
        int n = tid / 384, k = tid % 384;
        W1t[tid] = f2b(W1[k * 256 + n]);
    } else {
        int t2 = tid - 256 * 384;
        if (t2 < 128 * 256) {
            int o = t2 / 256, k = t2 % 256;
            W2t[t2] = f2b(W2[k * 128 + o]);
        }
    }
}

// Xb[n][d] = bf16(x[n][d]) — 12.8 MB gather table
__global__ __launch_bounds__(256)
void prep_x(const float* __restrict__ x, ushort* __restrict__ Xb, long total8) {
    long t = (long)blockIdx.x * blockDim.x + threadIdx.x;
    if (t < total8) {
        const float* src = x + t * 8;
        float4 v0 = ((const float4*)src)[0], v1 = ((const float4*)src)[1];
        union { bf16x8 v; ushort4 u[2]; } w;
        w.u[0] = cvt4(v0); w.u[1] = cvt4(v1);
        *(bf16x8*)(Xb + t * 8) = w.v;
    }
}

// R18: 2-tile pipeline (R17) with out-store CLUSTERED right after phase 2 —
// all 8 waves' stores issue in one tight window so L2 merges the 128B lines
// (R17 spread them across phase1+staging => partial-line writeback, +104MB).
__global__ __launch_bounds__(512, 2)
void edge_mlp15(const float* __restrict__ ea, const int* __restrict__ eidx,
                const ushort* __restrict__ Xb,
                const ushort* __restrict__ W1t, const ushort* __restrict__ W2t,
                const float* __restrict__ b1, const float* __restrict__ b2,
                float* __restrict__ out, int E, int ntiles) {
    __shared__ __align__(16) ushort sBuf[65536];   // 128 KB: sA0 | sA1 | sH
    ushort* sH = sBuf + 49152;

    const int tid = threadIdx.x;
    const int wave = tid >> 6, lane = tid & 63;
    const int row16 = lane & 15, kgrp = lane >> 4;
    const int srow = tid >> 3, oct = tid & 7;     // staging: 8 threads per edge-row

    // ---- persistent per-wave weight fragments ----
    bf16x8 w1f[12][2];      // phase1 (swapped): h-cols [wave*32,+32), ks spans K=384
    #pragma unroll
    for (int ks = 0; ks < 12; ++ks)
        #pragma unroll
        for (int fc = 0; fc < 2; ++fc)
            w1f[ks][fc] = *(const bf16x8*)(W1t + (wave * 32 + fc * 16 + row16) * K1 + ks * 32 + kgrp * 8);
    bf16x8 w2f[8];          // phase2: out cols [wave*16, +16)
    #pragma unroll
    for (int ks = 0; ks < 8; ++ks)
        w2f[ks] = *(const bf16x8*)(W2t + (wave * 16 + row16) * H + ks * 32 + kgrp * 8);
    float4 b1q[2];
    #pragma unroll
    for (int fc = 0; fc < 2; ++fc)
        b1q[fc] = *(const float4*)(b1 + wave * 32 + fc * 16 + kgrp * 4);
    const float b2v = b2[wave * 16 + row16];

    int t = blockIdx.x;
    if (t >= ntiles) return;

    bf16x8 pxs[2], pxr[2];
    f32x4  pea[4];

    // ---- prologue: stage tile t into sA[0] ----
    {
        long se = (long)t * BE + srow; if (se >= E) se = E - 1;
        int2 ei = *(const int2*)(eidx + 2 * se);
        const ushort* ps = Xb + (long)ei.x * D + oct * 16;
        const ushort* pr = Xb + (long)ei.y * D + oct * 16;
        const float*  pe = ea + se * D + oct * 16;
        #pragma unroll
        for (int j = 0; j < 2; ++j) pxs[j] = *(const bf16x8*)(ps + j * 8);
        #pragma unroll
        for (int j = 0; j < 2; ++j) pxr[j] = *(const bf16x8*)(pr + j * 8);
        #pragma unroll
        for (int j = 0; j < 4; ++j) pea[j] = ((const f32x4*)pe)[j];

        #pragma unroll
        for (int j = 0; j < 2; ++j) *(bf16x8*)(sBuf + SSW(srow, oct * 16 + j * 8)) = pxs[j];
        #pragma unroll
        for (int j = 0; j < 2; ++j) *(bf16x8*)(sBuf + 8192 + SSW(srow, oct * 16 + j * 8)) = pxr[j];
        *(bf16x8*)(sBuf + 16384 + SSW(srow, oct * 16 + 0)) = cvt8(pea[0], pea[1]);
        *(bf16x8*)(sBuf + 16384 + SSW(srow, oct * 16 + 8)) = cvt8(pea[2], pea[3]);
    }

    int p = 0;
    int tprev = -1;
    int tn = t + GRIDP;
    int2 ei2;
    {
        int tc = (tn < ntiles) ? tn : (ntiles - 1);
        long se = (long)tc * BE + srow; if (se >= E) se = E - 1;
        ei2 = *(const int2*)(eidx + 2 * se);
    }

    for (;;) {
        LGKM_BARRIER();                 // A: sA[p] (staged) + sH(tprev) visible
        const bool hasNext = (tn < ntiles);

        // ---- phase 2 of PREVIOUS tile + IMMEDIATE clustered out-store ----
        if (tprev >= 0) {
            f32x4 acc2[4];
            #pragma unroll
            for (int fr = 0; fr < 4; ++fr) acc2[fr] = (f32x4){0,0,0,0};
            #pragma unroll
            for (int ks = 0; ks < 8; ++ks) {
                bf16x8 a[4];
                #pragma unroll
                for (int fr = 0; fr < 4; ++fr)
                    a[fr] = *(const bf16x8*)(sH + HSW(fr * 16 + row16, ks * 32 + kgrp * 8));
                #pragma unroll
                for (int fr = 0; fr < 4; ++fr)
                    acc2[fr] = __builtin_amdgcn_mfma_f32_16x16x32_bf16(a[fr], w2f[ks], acc2[fr], 0, 0, 0);
            }
            const long e0p = (long)tprev * BE;
            #pragma unroll
            for (int fr = 0; fr < 4; ++fr)
                #pragma unroll
                for (int r = 0; r < 4; ++r) {
                    long erow = e0p + fr * 16 + kgrp * 4 + r;
                    if (erow < E) out[erow * O + wave * 16 + row16] = acc2[fr][r] + b2v;
                }
        }

        // ---- issue next tile's loads (hide under phase1) ----
        if (hasNext) {
            long sen = (long)tn * BE + srow; if (sen >= E) sen = E - 1;
            const ushort* ps = Xb + (long)ei2.x * D + oct * 16;
            const ushort* pr = Xb + (long)ei2.y * D + oct * 16;
            const float*  pe = ea + sen * D + oct * 16;
            #pragma unroll
            for (int j = 0; j < 2; ++j) pxs[j] = *(const bf16x8*)(ps + j * 8);
            #pragma unroll
            for (int j = 0; j < 2; ++j) pxr[j] = *(const bf16x8*)(pr + j * 8);
            #pragma unroll
            for (int j = 0; j < 4; ++j) pea[j] = ((const f32x4*)pe)[j];
            int tnn = tn + GRIDP;
            int tc = (tnn < ntiles) ? tnn : (ntiles - 1);
            long se2 = (long)tc * BE + srow; if (se2 >= E) se2 = E - 1;
            ei2 = *(const int2*)(eidx + 2 * se2);
        }

        // ---- phase 1 of CURRENT tile (swapped): acc[fe][fc] -> D[h-col][edge] ----
        const ushort* sA = sBuf + (p ? 24576 : 0);
        f32x4 acc[4][2];
        #pragma unroll
        for (int fe = 0; fe < 4; ++fe) { acc[fe][0] = (f32x4){0,0,0,0}; acc[fe][1] = (f32x4){0,0,0,0}; }
        #pragma unroll
        for (int ks = 0; ks < 12; ++ks) {
            const ushort* sP = sA + ((ks < 4) ? 0 : ((ks < 8) ? 8192 : 16384));
            const int kl = (ks & 3) * 32 + kgrp * 8;
            bf16x8 a[4];
            #pragma unroll
            for (int fe = 0; fe < 4; ++fe)
                a[fe] = *(const bf16x8*)(sP + SSW(fe * 16 + row16, kl));
            #pragma unroll
            for (int fe = 0; fe < 4; ++fe) {
                acc[fe][0] = __builtin_amdgcn_mfma_f32_16x16x32_bf16(w1f[ks][0], a[fe], acc[fe][0], 0, 0, 0);
                acc[fe][1] = __builtin_amdgcn_mfma_f32_16x16x32_bf16(w1f[ks][1], a[fe], acc[fe][1], 0, 0, 0);
            }
        }

        // ---- staging write(t+1) -> sA[p^1] (last read one epoch ago) ----
        if (hasNext) {
            ushort* sB = sBuf + (p ? 0 : 24576);
            #pragma unroll
            for (int j = 0; j < 2; ++j) *(bf16x8*)(sB + SSW(srow, oct * 16 + j * 8)) = pxs[j];
            #pragma unroll
            for (int j = 0; j < 2; ++j) *(bf16x8*)(sB + 8192 + SSW(srow, oct * 16 + j * 8)) = pxr[j];
            *(bf16x8*)(sB + 16384 + SSW(srow, oct * 16 + 0)) = cvt8(pea[0], pea[1]);
            *(bf16x8*)(sB + 16384 + SSW(srow, oct * 16 + 8)) = cvt8(pea[2], pea[3]);
        }

        LGKM_BARRIER();                 // B: all phase-2 reads of sH done

        // ---- sH write(t): relu(acc) -> sH (visible at next barrier A) ----
        #pragma unroll
        for (int fe = 0; fe < 4; ++fe) {
            int erow = fe * 16 + row16;
            int base = erow * 256;
            int swz = (erow & 7) << 3;
            #pragma unroll
            for (int fc = 0; fc < 2; ++fc) {
                int colb = wave * 32 + fc * 16 + kgrp * 4;
                ushort4 u;
                u.x = f2b(fmaxf(acc[fe][fc][0] + b1q[fc].x, 0.f));
                u.y = f2b(fmaxf(acc[fe][fc][1] + b1q[fc].y, 0.f));
                u.z = f2b(fmaxf(acc[fe][fc][2] + b1q[fc].z, 0.f));
                u.w = f2b(fmaxf(acc[fe][fc][3] + b1q[fc].w, 0.f));
                *(ushort4*)(sH + base + (colb ^ swz)) = u;
            }
        }

        tprev = t; t = tn; tn += GRIDP;
        if (t >= ntiles) break;
        p ^= 1;
    }

    // ---- epilogue: phase2 + store of the last tile ----
    LGKM_BARRIER();
    {
        f32x4 acc2[4];
        #pragma unroll
        for (int fr = 0; fr < 4; ++fr) acc2[fr] = (f32x4){0,0,0,0};
        #pragma unroll
        for (int ks = 0; ks < 8; ++ks) {
            bf16x8 a[4];
            #pragma unroll
            for (int fr = 0; fr < 4; ++fr)
                a[fr] = *(const bf16x8*)(sH + HSW(fr * 16 + row16, ks * 32 + kgrp * 8));
            #pragma unroll
            for (int fr = 0; fr < 4; ++fr)
                acc2[fr] = __builtin_amdgcn_mfma_f32_16x16x32_bf16(a[fr], w2f[ks], acc2[fr], 0, 0, 0);
        }
        const long e0p = (long)tprev * BE;
        #pragma unroll
        for (int fr = 0; fr < 4; ++fr)
            #pragma unroll
            for (int r = 0; r < 4; ++r) {
                long erow = e0p + fr * 16 + kgrp * 4 + r;
                if (erow < E) out[erow * O + wave * 16 + row16] = acc2[fr][r] + b2v;
            }
    }
}

// ---------------- fallback kernel: used only if ws too small ----------------
__global__ __launch_bounds__(256, 2)
void edge_mlp(const float* __restrict__ x, const float* __restrict__ ea,
              const int* __restrict__ eidx,
              const float* __restrict__ b1, const float* __restrict__ b2,
              const ushort* __restrict__ W1t, const ushort* __restrict__ W2t,
              float* __restrict__ out, int E) {
    __shared__ ushort sF[64 * LDF];
    ushort* sH = sF;
    const int tid = threadIdx.x, wave = tid >> 6, lane = tid & 63;
    const int row16 = lane & 15, kgrp = lane >> 4;
    const long e0 = (long)blockIdx.x * 64;
    {
        int i = tid >> 2, p = tid & 3;
        long e = e0 + i; if (e >= E) e = E - 1;
        int s = eidx[2 * e], r = eidx[2 * e + 1];
        const float* src0 = x + (long)s * D + p * 32;
        const float* src1 = x + (long)r * D + p * 32;
        const float* src2 = ea + e * D + p * 32;
        ushort* dst = sF + i * LDF + p * 32;
        #pragma unroll
        for (int j = 0; j < 8; ++j) *(ushort4*)(dst + 0 * D + j * 4) = cvt4(((const float4*)src0)[j]);
        #pragma unroll
        for (int j = 0; j < 8; ++j) *(ushort4*)(dst + 1 * D + j * 4) = cvt4(((const float4*)src1)[j]);
        #pragma unroll
        for (int j = 0; j < 8; ++j) *(ushort4*)(dst + 2 * D + j * 4) = cvt4(((const float4*)src2)[j]);
    }
    __syncthreads();
    f32x4 acc[4][4];
    #pragma unroll
    for (int a = 0; a < 4; ++a)
        #pragma unroll
        for (int b = 0; b < 4; ++b) acc[a][b] = (f32x4){0,0,0,0};
    const int wcol = wave * 64;
    for (int k0 = 0; k0 < K1; k0 += 32) {
        bf16x8 a[4], b[4];
        #pragma unroll
        for (int fr = 0; fr < 4; ++fr)
            a[fr] = *(const bf16x8*)(sF + (fr * 16 + row16) * LDF + k0 + kgrp * 8);
        #pragma unroll
        for (int fc = 0; fc < 4; ++fc)
            b[fc] = *(const bf16x8*)(W1t + (wcol + fc * 16 + row16) * K1 + k0 + kgrp * 8);
        #pragma unroll
        for (int fr = 0; fr < 4; ++fr)
            #pragma unroll
            for (int fc = 0; fc < 4; ++fc)
                acc[fr][fc] = __builtin_amdgcn_mfma_f32_16x16x32_bf16(a[fr], b[fc], acc[fr][fc], 0, 0, 0);
    }
    __syncthreads();
    #pragma unroll
    for (int fc = 0; fc < 4; ++fc) {
        int col = wcol + fc * 16 + row16;
        float bv = b1[col];
        #pragma unroll
        for (int fr = 0; fr < 4; ++fr)
            #pragma unroll
            for (int r = 0; r < 4; ++r) {
                int row = fr * 16 + kgrp * 4 + r;
                sH[row * LDHF + col] = f2b(fmaxf(acc[fr][fc][r] + bv, 0.f));
            }
    }
    __syncthreads();
    f32x4 acc2[4][2];
    #pragma unroll
    for (int a = 0; a < 4; ++a)
        #pragma unroll
        for (int b = 0; b < 2; ++b) acc2[a][b] = (f32x4){0,0,0,0};
    const int wo = wave * 32;
    for (int k0 = 0; k0 < H; k0 += 32) {
        bf16x8 a[4], b[2];
        #pragma unroll
        for (int fr = 0; fr < 4; ++fr)
            a[fr] = *(const bf16x8*)(sH + (fr * 16 + row16) * LDHF + k0 + kgrp * 8);
        #pragma unroll
        for (int fc = 0; fc < 2; ++fc)
            b[fc] = *(const bf16x8*)(W2t + (wo + fc * 16 + row16) * H + k0 + kgrp * 8);
        #pragma unroll
        for (int fr = 0; fr < 4; ++fr)
            #pragma unroll
            for (int fc = 0; fc < 2; ++fc)
                acc2[fr][fc] = __builtin_amdgcn_mfma_f32_16x16x32_bf16(a[fr], b[fc], acc2[fr][fc], 0, 0, 0);
    }
    #pragma unroll
    for (int fc = 0; fc < 2; ++fc) {
        int col = wo + fc * 16 + row16;
        float bv = b2[col];
        #pragma unroll
        for (int fr = 0; fr < 4; ++fr)
            #pragma unroll
            for (int r = 0; r < 4; ++r) {
                long row = e0 + fr * 16 + kgrp * 4 + r;
                if (row < E) out[row * O + col] = acc2[fr][fc][r] + bv;
            }
    }
}

extern "C" void kernel_launch(void* const* d_in, const int* in_sizes, int n_in,
                              void* d_out, int out_size, void* d_ws, size_t ws_size,
                              hipStream_t stream) {
    const float* x  = (const float*)d_in[0];
    const float* ea = (const float*)d_in[1];
    const float* W1 = (const float*)d_in[2];
    const float* b1 = (const float*)d_in[3];
    const float* W2 = (const float*)d_in[4];
    const float* b2 = (const float*)d_in[5];
    const int* eidx = (const int*)d_in[6];
    float* out = (float*)d_out;

    const int E = in_sizes[1] / D;          // 500000
    const int N = in_sizes[0] / D;          // 50000

    ushort* W1t = (ushort*)d_ws;                    // 256*384
    ushort* W2t = W1t + 256 * 384;                  // 128*256
    ushort* Xb  = W2t + 128 * 256;                  // N*128 (12.8 MB)
    size_t need = ((size_t)(256 * 384 + 128 * 256) + (size_t)N * 128) * 2;

    prep_weights<<<512, 256, 0, stream>>>(W1, W2, W1t, W2t);

    if (ws_size >= need) {
        long total8 = (long)N * D / 8;
        int nbx = (int)((total8 + 255) / 256);
        prep_x<<<nbx, 256, 0, stream>>>(x, Xb, total8);
        int ntiles = (E + BE - 1) / BE;
        int grid = (ntiles < GRIDP) ? ntiles : GRIDP;
        edge_mlp15<<<grid, 512, 0, stream>>>(ea, eidx, Xb, W1t, W2t, b1, b2, out, E, ntiles);
    } else {
        int nb = (E + 63) / 64;
        edge_mlp<<<nb, 256, 0, stream>>>(x, ea, eidx, b1, b2, W1t, W2t, out, E);
    }
}

// Round 19
// 190.127 us; speedup vs baseline: 1.2288x; 1.0733x over previous
//
#include <hip/hip_runtime.h>
#include <hip/hip_bf16.h>

#define D 128
#define K1 384
#define H 256
#define O 128
#define BE 64
#define GRIDP 256
#define LDF (K1 + 8)   // fallback path feat leading dim
#define LDHF (H + 8)

typedef __attribute__((ext_vector_type(8))) short bf16x8;
typedef __attribute__((ext_vector_type(4))) float f32x4;

// XOR-swizzle, widened to (row&15): row stride is 0 mod 32 banks, and frag reads
// span 16 rows x 4 kgrps -> 4-bit XOR halves lane clustering vs (row&7) (R18: 25M conflicts).
#define SSW(row, col) ((row) * 128 + ((col) ^ (((row) & 15) << 3)))   // staging tiles, col<128
#define HSW(row, col) ((row) * 256 + ((col) ^ (((row) & 15) << 3)))   // h tile, col<256

// lgkm-only barrier: orders LDS, does NOT drain vmcnt (prefetch stays in flight).
#define LGKM_BARRIER()                                                 \
    do {                                                               \
        asm volatile("s_waitcnt lgkmcnt(0)\n\ts_barrier" ::: "memory");\
        __builtin_amdgcn_sched_barrier(0);                             \
    } while (0)

__device__ inline ushort f2b(float f) {
    union { float f; unsigned u; } v; v.f = f;
    unsigned u = v.u;
    unsigned r = (u + 0x7fffu + ((u >> 16) & 1u)) >> 16;   // RNE
    return (ushort)r;
}
__device__ inline ushort4 cvt4(float4 v) {
    ushort4 u; u.x = f2b(v.x); u.y = f2b(v.y); u.z = f2b(v.z); u.w = f2b(v.w); return u;
}
// HW packed f32x2 -> bf16x2 (1 VALU op vs ~8 for manual RNE); gfx950 has no builtin.
__device__ inline unsigned cvtpk(float lo, float hi) {
    unsigned r;
    asm("v_cvt_pk_bf16_f32 %0, %1, %2" : "=v"(r) : "v"(lo), "v"(hi));
    return r;
}
__device__ inline bf16x8 cvt8(f32x4 a, f32x4 b) {
    union { bf16x8 v; unsigned w[4]; } u;
    u.w[0] = cvtpk(a[0], a[1]); u.w[1] = cvtpk(a[2], a[3]);
    u.w[2] = cvtpk(b[0], b[1]); u.w[3] = cvtpk(b[2], b[3]);
    return u.v;
}

// W1t[n][k] = bf16(W1[k][n]) (n<256,k<384) ; W2t[o][k] = bf16(W2[k][o]) (o<128,k<256)
__global__ void prep_weights(const float* __restrict__ W1, const float* __restrict__ W2,
                             ushort* __restrict__ W1t, ushort* __restrict__ W2t) {
    int tid = blockIdx.x * blockDim.x + threadIdx.x;
    if (tid < 256 * 384) {
        int n = tid / 384, k = tid % 384;
        W1t[tid] = f2b(W1[k * 256 + n]);
    } else {
        int t2 = tid - 256 * 384;
        if (t2 < 128 * 256) {
            int o = t2 / 256, k = t2 % 256;
            W2t[t2] = f2b(W2[k * 128 + o]);
        }
    }
}

// Xb[n][d] = bf16(x[n][d]) — 12.8 MB gather table
__global__ __launch_bounds__(256)
void prep_x(const float* __restrict__ x, ushort* __restrict__ Xb, long total8) {
    long t = (long)blockIdx.x * blockDim.x + threadIdx.x;
    if (t < total8) {
        const float* src = x + t * 8;
        float4 v0 = ((const float4*)src)[0], v1 = ((const float4*)src)[1];
        union { bf16x8 v; ushort4 u[2]; } w;
        w.u[0] = cvt4(v0); w.u[1] = cvt4(v1);
        *(bf16x8*)(Xb + t * 8) = w.v;
    }
}

// R19 = R18 (2-tile pipeline, clustered stores) + (row&15) swizzle + cvt_pk conversions.
__global__ __launch_bounds__(512, 2)
void edge_mlp16(const float* __restrict__ ea, const int* __restrict__ eidx,
                const ushort* __restrict__ Xb,
                const ushort* __restrict__ W1t, const ushort* __restrict__ W2t,
                const float* __restrict__ b1, const float* __restrict__ b2,
                float* __restrict__ out, int E, int ntiles) {
    __shared__ __align__(16) ushort sBuf[65536];   // 128 KB: sA0 | sA1 | sH
    ushort* sH = sBuf + 49152;

    const int tid = threadIdx.x;
    const int wave = tid >> 6, lane = tid & 63;
    const int row16 = lane & 15, kgrp = lane >> 4;
    const int srow = tid >> 3, oct = tid & 7;     // staging: 8 threads per edge-row

    // ---- persistent per-wave weight fragments ----
    bf16x8 w1f[12][2];      // phase1 (swapped): h-cols [wave*32,+32), ks spans K=384
    #pragma unroll
    for (int ks = 0; ks < 12; ++ks)
        #pragma unroll
        for (int fc = 0; fc < 2; ++fc)
            w1f[ks][fc] = *(const bf16x8*)(W1t + (wave * 32 + fc * 16 + row16) * K1 + ks * 32 + kgrp * 8);
    bf16x8 w2f[8];          // phase2: out cols [wave*16, +16)
    #pragma unroll
    for (int ks = 0; ks < 8; ++ks)
        w2f[ks] = *(const bf16x8*)(W2t + (wave * 16 + row16) * H + ks * 32 + kgrp * 8);
    float4 b1q[2];
    #pragma unroll
    for (int fc = 0; fc < 2; ++fc)
        b1q[fc] = *(const float4*)(b1 + wave * 32 + fc * 16 + kgrp * 4);
    const float b2v = b2[wave * 16 + row16];

    int t = blockIdx.x;
    if (t >= ntiles) return;

    bf16x8 pxs[2], pxr[2];
    f32x4  pea[4];

    // ---- prologue: stage tile t into sA[0] ----
    {
        long se = (long)t * BE + srow; if (se >= E) se = E - 1;
        int2 ei = *(const int2*)(eidx + 2 * se);
        const ushort* ps = Xb + (long)ei.x * D + oct * 16;
        const ushort* pr = Xb + (long)ei.y * D + oct * 16;
        const float*  pe = ea + se * D + oct * 16;
        #pragma unroll
        for (int j = 0; j < 2; ++j) pxs[j] = *(const bf16x8*)(ps + j * 8);
        #pragma unroll
        for (int j = 0; j < 2; ++j) pxr[j] = *(const bf16x8*)(pr + j * 8);
        #pragma unroll
        for (int j = 0; j < 4; ++j) pea[j] = ((const f32x4*)pe)[j];

        #pragma unroll
        for (int j = 0; j < 2; ++j) *(bf16x8*)(sBuf + SSW(srow, oct * 16 + j * 8)) = pxs[j];
        #pragma unroll
        for (int j = 0; j < 2; ++j) *(bf16x8*)(sBuf + 8192 + SSW(srow, oct * 16 + j * 8)) = pxr[j];
        *(bf16x8*)(sBuf + 16384 + SSW(srow, oct * 16 + 0)) = cvt8(pea[0], pea[1]);
        *(bf16x8*)(sBuf + 16384 + SSW(srow, oct * 16 + 8)) = cvt8(pea[2], pea[3]);
    }

    int p = 0;
    int tprev = -1;
    int tn = t + GRIDP;
    int2 ei2;
    {
        int tc = (tn < ntiles) ? tn : (ntiles - 1);
        long se = (long)tc * BE + srow; if (se >= E) se = E - 1;
        ei2 = *(const int2*)(eidx + 2 * se);
    }

    for (;;) {
        LGKM_BARRIER();                 // A: sA[p] (staged) + sH(tprev) visible
        const bool hasNext = (tn < ntiles);

        // ---- phase 2 of PREVIOUS tile + IMMEDIATE clustered out-store ----
        if (tprev >= 0) {
            f32x4 acc2[4];
            #pragma unroll
            for (int fr = 0; fr < 4; ++fr) acc2[fr] = (f32x4){0,0,0,0};
            #pragma unroll
            for (int ks = 0; ks < 8; ++ks) {
                bf16x8 a[4];
                #pragma unroll
                for (int fr = 0; fr < 4; ++fr)
                    a[fr] = *(const bf16x8*)(sH + HSW(fr * 16 + row16, ks * 32 + kgrp * 8));
                #pragma unroll
                for (int fr = 0; fr < 4; ++fr)
                    acc2[fr] = __builtin_amdgcn_mfma_f32_16x16x32_bf16(a[fr], w2f[ks], acc2[fr], 0, 0, 0);
            }
            const long e0p = (long)tprev * BE;
            #pragma unroll
            for (int fr = 0; fr < 4; ++fr)
                #pragma unroll
                for (int r = 0; r < 4; ++r) {
                    long erow = e0p + fr * 16 + kgrp * 4 + r;
                    if (erow < E) out[erow * O + wave * 16 + row16] = acc2[fr][r] + b2v;
                }
        }

        // ---- issue next tile's loads (hide under phase1) ----
        if (hasNext) {
            long sen = (long)tn * BE + srow; if (sen >= E) sen = E - 1;
            const ushort* ps = Xb + (long)ei2.x * D + oct * 16;
            const ushort* pr = Xb + (long)ei2.y * D + oct * 16;
            const float*  pe = ea + sen * D + oct * 16;
            #pragma unroll
            for (int j = 0; j < 2; ++j) pxs[j] = *(const bf16x8*)(ps + j * 8);
            #pragma unroll
            for (int j = 0; j < 2; ++j) pxr[j] = *(const bf16x8*)(pr + j * 8);
            #pragma unroll
            for (int j = 0; j < 4; ++j) pea[j] = ((const f32x4*)pe)[j];
            int tnn = tn + GRIDP;
            int tc = (tnn < ntiles) ? tnn : (ntiles - 1);
            long se2 = (long)tc * BE + srow; if (se2 >= E) se2 = E - 1;
            ei2 = *(const int2*)(eidx + 2 * se2);
        }

        // ---- phase 1 of CURRENT tile (swapped): acc[fe][fc] -> D[h-col][edge] ----
        const ushort* sA = sBuf + (p ? 24576 : 0);
        f32x4 acc[4][2];
        #pragma unroll
        for (int fe = 0; fe < 4; ++fe) { acc[fe][0] = (f32x4){0,0,0,0}; acc[fe][1] = (f32x4){0,0,0,0}; }
        #pragma unroll
        for (int ks = 0; ks < 12; ++ks) {
            const ushort* sP = sA + ((ks < 4) ? 0 : ((ks < 8) ? 8192 : 16384));
            const int kl = (ks & 3) * 32 + kgrp * 8;
            bf16x8 a[4];
            #pragma unroll
            for (int fe = 0; fe < 4; ++fe)
                a[fe] = *(const bf16x8*)(sP + SSW(fe * 16 + row16, kl));
            #pragma unroll
            for (int fe = 0; fe < 4; ++fe) {
                acc[fe][0] = __builtin_amdgcn_mfma_f32_16x16x32_bf16(w1f[ks][0], a[fe], acc[fe][0], 0, 0, 0);
                acc[fe][1] = __builtin_amdgcn_mfma_f32_16x16x32_bf16(w1f[ks][1], a[fe], acc[fe][1], 0, 0, 0);
            }
        }

        // ---- staging write(t+1) -> sA[p^1] (last read one epoch ago) ----
        if (hasNext) {
            ushort* sB = sBuf + (p ? 0 : 24576);
            #pragma unroll
            for (int j = 0; j < 2; ++j) *(bf16x8*)(sB + SSW(srow, oct * 16 + j * 8)) = pxs[j];
            #pragma unroll
            for (int j = 0; j < 2; ++j) *(bf16x8*)(sB + 8192 + SSW(srow, oct * 16 + j * 8)) = pxr[j];
            *(bf16x8*)(sB + 16384 + SSW(srow, oct * 16 + 0)) = cvt8(pea[0], pea[1]);
            *(bf16x8*)(sB + 16384 + SSW(srow, oct * 16 + 8)) = cvt8(pea[2], pea[3]);
        }

        LGKM_BARRIER();                 // B: all phase-2 reads of sH done

        // ---- sH write(t): relu(acc) -> sH via cvt_pk (visible at next barrier A) ----
        #pragma unroll
        for (int fe = 0; fe < 4; ++fe) {
            int erow = fe * 16 + row16;
            int base = erow * 256;
            int swz = (erow & 15) << 3;
            #pragma unroll
            for (int fc = 0; fc < 2; ++fc) {
                int colb = wave * 32 + fc * 16 + kgrp * 4;
                union { uint2 w; ushort4 u; } pk;
                pk.w.x = cvtpk(fmaxf(acc[fe][fc][0] + b1q[fc].x, 0.f),
                               fmaxf(acc[fe][fc][1] + b1q[fc].y, 0.f));
                pk.w.y = cvtpk(fmaxf(acc[fe][fc][2] + b1q[fc].z, 0.f),
                               fmaxf(acc[fe][fc][3] + b1q[fc].w, 0.f));
                *(ushort4*)(sH + base + (colb ^ swz)) = pk.u;
            }
        }

        tprev = t; t = tn; tn += GRIDP;
        if (t >= ntiles) break;
        p ^= 1;
    }

    // ---- epilogue: phase2 + store of the last tile ----
    LGKM_BARRIER();
    {
        f32x4 acc2[4];
        #pragma unroll
        for (int fr = 0; fr < 4; ++fr) acc2[fr] = (f32x4){0,0,0,0};
        #pragma unroll
        for (int ks = 0; ks < 8; ++ks) {
            bf16x8 a[4];
            #pragma unroll
            for (int fr = 0; fr < 4; ++fr)
                a[fr] = *(const bf16x8*)(sH + HSW(fr * 16 + row16, ks * 32 + kgrp * 8));
            #pragma unroll
            for (int fr = 0; fr < 4; ++fr)
                acc2[fr] = __builtin_amdgcn_mfma_f32_16x16x32_bf16(a[fr], w2f[ks], acc2[fr], 0, 0, 0);
        }
        const long e0p = (long)tprev * BE;
        #pragma unroll
        for (int fr = 0; fr < 4; ++fr)
            #pragma unroll
            for (int r = 0; r < 4; ++r) {
                long erow = e0p + fr * 16 + kgrp * 4 + r;
                if (erow < E) out[erow * O + wave * 16 + row16] = acc2[fr][r] + b2v;
            }
    }
}

// ---------------- fallback kernel: used only if ws too small ----------------
__global__ __launch_bounds__(256, 2)
void edge_mlp(const float* __restrict__ x, const float* __restrict__ ea,
              const int* __restrict__ eidx,
              const float* __restrict__ b1, const float* __restrict__ b2,
              const ushort* __restrict__ W1t, const ushort* __restrict__ W2t,
              float* __restrict__ out, int E) {
    __shared__ ushort sF[64 * LDF];
    ushort* sH = sF;
    const int tid = threadIdx.x, wave = tid >> 6, lane = tid & 63;
    const int row16 = lane & 15, kgrp = lane >> 4;
    const long e0 = (long)blockIdx.x * 64;
    {
        int i = tid >> 2, p = tid & 3;
        long e = e0 + i; if (e >= E) e = E - 1;
        int s = eidx[2 * e], r = eidx[2 * e + 1];
        const float* src0 = x + (long)s * D + p * 32;
        const float* src1 = x + (long)r * D + p * 32;
        const float* src2 = ea + e * D + p * 32;
        ushort* dst = sF + i * LDF + p * 32;
        #pragma unroll
        for (int j = 0; j < 8; ++j) *(ushort4*)(dst + 0 * D + j * 4) = cvt4(((const float4*)src0)[j]);
        #pragma unroll
        for (int j = 0; j < 8; ++j) *(ushort4*)(dst + 1 * D + j * 4) = cvt4(((const float4*)src1)[j]);
        #pragma unroll
        for (int j = 0; j < 8; ++j) *(ushort4*)(dst + 2 * D + j * 4) = cvt4(((const float4*)src2)[j]);
    }
    __syncthreads();
    f32x4 acc[4][4];
    #pragma unroll
    for (int a = 0; a < 4; ++a)
        #pragma unroll
        for (int b = 0; b < 4; ++b) acc[a][b] = (f32x4){0,0,0,0};
    const int wcol = wave * 64;
    for (int k0 = 0; k0 < K1; k0 += 32) {
        bf16x8 a[4], b[4];
        #pragma unroll
        for (int fr = 0; fr < 4; ++fr)
            a[fr] = *(const bf16x8*)(sF + (fr * 16 + row16) * LDF + k0 + kgrp * 8);
        #pragma unroll
        for (int fc = 0; fc < 4; ++fc)
            b[fc] = *(const bf16x8*)(W1t + (wcol + fc * 16 + row16) * K1 + k0 + kgrp * 8);
        #pragma unroll
        for (int fr = 0; fr < 4; ++fr)
            #pragma unroll
            for (int fc = 0; fc < 4; ++fc)
                acc[fr][fc] = __builtin_amdgcn_mfma_f32_16x16x32_bf16(a[fr], b[fc], acc[fr][fc], 0, 0, 0);
    }
    __syncthreads();
    #pragma unroll
    for (int fc = 0; fc < 4; ++fc) {
        int col = wcol + fc * 16 + row16;
        float bv = b1[col];
        #pragma unroll
        for (int fr = 0; fr < 4; ++fr)
            #pragma unroll
            for (int r = 0; r < 4; ++r) {
                int row = fr * 16 + kgrp * 4 + r;
                sH[row * LDHF + col] = f2b(fmaxf(acc[fr][fc][r] + bv, 0.f));
            }
    }
    __syncthreads();
    f32x4 acc2[4][2];
    #pragma unroll
    for (int a = 0; a < 4; ++a)
        #pragma unroll
        for (int b = 0; b < 2; ++b) acc2[a][b] = (f32x4){0,0,0,0};
    const int wo = wave * 32;
    for (int k0 = 0; k0 < H; k0 += 32) {
        bf16x8 a[4], b[2];
        #pragma unroll
        for (int fr = 0; fr < 4; ++fr)
            a[fr] = *(const bf16x8*)(sH + (fr * 16 + row16) * LDHF + k0 + kgrp * 8);
        #pragma unroll
        for (int fc = 0; fc < 2; ++fc)
            b[fc] = *(const bf16x8*)(W2t + (wo + fc * 16 + row16) * H + k0 + kgrp * 8);
        #pragma unroll
        for (int fr = 0; fr < 4; ++fr)
            #pragma unroll
            for (int fc = 0; fc < 2; ++fc)
                acc2[fr][fc] = __builtin_amdgcn_mfma_f32_16x16x32_bf16(a[fr], b[fc], acc2[fr][fc], 0, 0, 0);
    }
    #pragma unroll
    for (int fc = 0; fc < 2; ++fc) {
        int col = wo + fc * 16 + row16;
        float bv = b2[col];
        #pragma unroll
        for (int fr = 0; fr < 4; ++fr)
            #pragma unroll
            for (int r = 0; r < 4; ++r) {
                long row = e0 + fr * 16 + kgrp * 4 + r;
                if (row < E) out[row * O + col] = acc2[fr][fc][r] + bv;
            }
    }
}

extern "C" void kernel_launch(void* const* d_in, const int* in_sizes, int n_in,
                              void* d_out, int out_size, void* d_ws, size_t ws_size,
                              hipStream_t stream) {
    const float* x  = (const float*)d_in[0];
    const float* ea = (const float*)d_in[1];
    const float* W1 = (const float*)d_in[2];
    const float* b1 = (const float*)d_in[3];
    const float* W2 = (const float*)d_in[4];
    const float* b2 = (const float*)d_in[5];
    const int* eidx = (const int*)d_in[6];
    float* out = (float*)d_out;

    const int E = in_sizes[1] / D;          // 500000
    const int N = in_sizes[0] / D;          // 50000

    ushort* W1t = (ushort*)d_ws;                    // 256*384
    ushort* W2t = W1t + 256 * 384;                  // 128*256
    ushort* Xb  = W2t + 128 * 256;                  // N*128 (12.8 MB)
    size_t need = ((size_t)(256 * 384 + 128 * 256) + (size_t)N * 128) * 2;

    prep_weights<<<512, 256, 0, stream>>>(W1, W2, W1t, W2t);

    if (ws_size >= need) {
        long total8 = (long)N * D / 8;
        int nbx = (int)((total8 + 255) / 256);
        prep_x<<<nbx, 256, 0, stream>>>(x, Xb, total8);
        int ntiles = (E + BE - 1) / BE;
        int grid = (ntiles < GRIDP) ? ntiles : GRIDP;
        edge_mlp16<<<grid, 512, 0, stream>>>(ea, eidx, Xb, W1t, W2t, b1, b2, out, E, ntiles);
    } else {
        int nb = (E + 63) / 64;
        edge_mlp<<<nb, 256, 0, stream>>>(x, ea, eidx, b1, b2, W1t, W2t, out, E);
    }
}